// Round 27
// baseline (88948.138 us; speedup 1.0000x reference)
//
#include <hip/hip_runtime.h>
#include <cstdio>

constexpr int kNB = 64;    // batch
constexpr int kNS = 512;   // encoder sequence length
constexpr int kNH = 512;   // hidden dim
constexpr int kNG = 2048;  // 4*kNH gate rows
constexpr int kNT = 512;   // decoder steps

static int g_once = 0;

__device__ __forceinline__ float chpn_sigmoid(float x) {
    return 1.0f / (1.0f + __expf(-x));
}
__device__ __forceinline__ float chpn_tanh(float x) {
    x = fmaxf(fminf(x, 15.0f), -15.0f);
    float e = __expf(2.0f * x);
    return (e - 1.0f) / (e + 1.0f);
}

// ------- init: zero h0/c, fused biases, transposed W_query ---------------
__global__ void ConvexHullPointerNetwork_57303453663418_kernel(
    const float* ebih, const float* ebhh,
    const float* dbih, const float* dbhh,
    const float* wq,
    float* enc_b, float* dec_b, float* wqT, float* h0c)
{
    int i = blockIdx.x * 256 + threadIdx.x;
    if (i < kNG) { enc_b[i] = ebih[i] + ebhh[i]; dec_b[i] = dbih[i] + dbhh[i]; }
    if (i < 2 * kNB * kNH) h0c[i] = 0.0f;
    if (i < kNH * kNH) {
        int r = i >> 9, c = i & 511;
        wqT[c * kNH + r] = wq[i];
    }
}

// ---------------- encoder cell (f32 staging) -----------------------------
__global__ void chpn_enc_cell(
    const float* inputs, const float* wih,
    const float* whh, const float* bias,
    const float* h_src, float* h_dst,
    float* c_st, float* enc_outs, int t)
{
    __shared__ float tile[64][65];
    __shared__ float gate_lds[4][2][64];
    const int tid = threadIdx.x;
    const int bb = tid & 63, gg = tid >> 6;
    const int j0 = (int)blockIdx.x * 2;

    const float* w0 = whh + (size_t)(gg * kNH + j0) * kNH;
    const float* w1 = w0 + kNH;
    float acc0 = 0.f, acc1 = 0.f;

    for (int ch = 0; ch < 8; ++ch) {
        const int k0 = ch * 64;
        for (int i = 0; i < 16; ++i) {
            int e = tid + i * 256; int kk = e & 63, b2 = e >> 6;
            tile[kk][b2] = h_src[b2 * kNH + k0 + kk];
        }
        __syncthreads();
        for (int kk = 0; kk < 64; ++kk) {
            float hv = tile[kk][bb];
            acc0 = fmaf(hv, w0[k0 + kk], acc0);
            acc1 = fmaf(hv, w1[k0 + kk], acc1);
        }
        __syncthreads();
    }
    float x0 = inputs[(bb * kNS + t) * 2 + 0];
    float x1 = inputs[(bb * kNS + t) * 2 + 1];
    int r0 = gg * kNH + j0;
    acc0 += bias[r0]     + wih[r0 * 2] * x0       + wih[r0 * 2 + 1] * x1;
    acc1 += bias[r0 + 1] + wih[(r0 + 1) * 2] * x0 + wih[(r0 + 1) * 2 + 1] * x1;

    gate_lds[gg][0][bb] = acc0;
    gate_lds[gg][1][bb] = acc1;
    __syncthreads();
    if (tid < 128) {
        int b2 = tid & 63, jd = tid >> 6;
        int j = j0 + jd;
        float gi = gate_lds[0][jd][b2], gf = gate_lds[1][jd][b2];
        float gc = gate_lds[2][jd][b2], go = gate_lds[3][jd][b2];
        float cc = chpn_sigmoid(gf) * c_st[b2 * kNH + j] + chpn_sigmoid(gi) * chpn_tanh(gc);
        float hh = chpn_sigmoid(go) * chpn_tanh(cc);
        c_st[b2 * kNH + j] = cc;
        h_dst[b2 * kNH + j] = hh;
        enc_outs[((size_t)b2 * kNS + t) * kNH + j] = hh;
    }
}

// -------- keysT[b][h][s] GEMM (f32) --------------------------------------
__global__ void chpn_keys_gemm(
    const float* enc_outs, const float* wk, float* keysT)
{
    int bid = blockIdx.x;
    int bb = bid >> 6, ht = (bid >> 3) & 7, st = bid & 7;
    __shared__ float asb[32][66];
    __shared__ float bsb[32][66];
    int tid = threadIdx.x;
    int tx = tid & 15, ty = tid >> 4;
    float acc[4][4] = {};
    for (int j0 = 0; j0 < kNH; j0 += 32) {
        for (int i = 0; i < 8; ++i) {
            int e = tid + i * 256;
            int j = e & 31, s = e >> 5;
            asb[j][s] = enc_outs[((size_t)bb * kNS + st * 64 + s) * kNH + j0 + j];
            bsb[j][s] = wk[(size_t)(ht * 64 + s) * kNH + j0 + j];
        }
        __syncthreads();
        for (int j = 0; j < 32; ++j) {
            float a0 = asb[j][tx*4], a1 = asb[j][tx*4+1], a2 = asb[j][tx*4+2], a3 = asb[j][tx*4+3];
            float b0 = bsb[j][ty*4], b1 = bsb[j][ty*4+1], b2 = bsb[j][ty*4+2], b3 = bsb[j][ty*4+3];
            acc[0][0] = fmaf(b0,a0,acc[0][0]); acc[0][1] = fmaf(b0,a1,acc[0][1]);
            acc[0][2] = fmaf(b0,a2,acc[0][2]); acc[0][3] = fmaf(b0,a3,acc[0][3]);
            acc[1][0] = fmaf(b1,a0,acc[1][0]); acc[1][1] = fmaf(b1,a1,acc[1][1]);
            acc[1][2] = fmaf(b1,a2,acc[1][2]); acc[1][3] = fmaf(b1,a3,acc[1][3]);
            acc[2][0] = fmaf(b2,a0,acc[2][0]); acc[2][1] = fmaf(b2,a1,acc[2][1]);
            acc[2][2] = fmaf(b2,a2,acc[2][2]); acc[2][3] = fmaf(b2,a3,acc[2][3]);
            acc[3][0] = fmaf(b3,a0,acc[3][0]); acc[3][1] = fmaf(b3,a1,acc[3][1]);
            acc[3][2] = fmaf(b3,a2,acc[3][2]); acc[3][3] = fmaf(b3,a3,acc[3][3]);
        }
        __syncthreads();
    }
    for (int i = 0; i < 4; ++i)
        for (int k = 0; k < 4; ++k)
            keysT[((size_t)bb * kNH + ht * 64 + ty * 4 + i) * kNS + st * 64 + tx * 4 + k] =
                acc[i][k];
}

// ---------------- decoder cell (x = ctx_num/denom of prev step) ----------
__global__ void chpn_dec_cell(
    const float* wih, const float* whh, const float* bias,
    const float* h_src, float* h_dst, float* c_st,
    const float* ctx_num, const float* denom, int first)
{
    __shared__ float tile[64][65];
    __shared__ float gate_lds[4][2][64];
    __shared__ float invd[64];
    const int tid = threadIdx.x;
    const int bb = tid & 63, gg = tid >> 6;
    const int j0 = (int)blockIdx.x * 2;
    if (tid < 64) invd[tid] = first ? 0.0f : (1.0f / denom[tid]);
    __syncthreads();
    float acc0 = 0.f, acc1 = 0.f;

    {   // x half (context)
        const float* w0 = wih + (size_t)(gg * kNH + j0) * kNH;
        const float* w1 = w0 + kNH;
        for (int ch = 0; ch < 8; ++ch) {
            const int k0 = ch * 64;
            for (int i = 0; i < 16; ++i) {
                int e = tid + i * 256; int kk = e & 63, b2 = e >> 6;
                tile[kk][b2] = first ? 0.0f : ctx_num[b2 * kNH + k0 + kk] * invd[b2];
            }
            __syncthreads();
            for (int kk = 0; kk < 64; ++kk) {
                float sv = tile[kk][bb];
                acc0 = fmaf(sv, w0[k0 + kk], acc0);
                acc1 = fmaf(sv, w1[k0 + kk], acc1);
            }
            __syncthreads();
        }
    }
    {   // h half
        const float* w0 = whh + (size_t)(gg * kNH + j0) * kNH;
        const float* w1 = w0 + kNH;
        for (int ch = 0; ch < 8; ++ch) {
            const int k0 = ch * 64;
            for (int i = 0; i < 16; ++i) {
                int e = tid + i * 256; int kk = e & 63, b2 = e >> 6;
                tile[kk][b2] = h_src[b2 * kNH + k0 + kk];
            }
            __syncthreads();
            for (int kk = 0; kk < 64; ++kk) {
                float sv = tile[kk][bb];
                acc0 = fmaf(sv, w0[k0 + kk], acc0);
                acc1 = fmaf(sv, w1[k0 + kk], acc1);
            }
            __syncthreads();
        }
    }
    acc0 += bias[gg * kNH + j0];
    acc1 += bias[gg * kNH + j0 + 1];
    gate_lds[gg][0][bb] = acc0;
    gate_lds[gg][1][bb] = acc1;
    __syncthreads();
    if (tid < 128) {
        int b2 = tid & 63, jd = tid >> 6;
        int j = j0 + jd;
        float gi = gate_lds[0][jd][b2], gf = gate_lds[1][jd][b2];
        float gc = gate_lds[2][jd][b2], go = gate_lds[3][jd][b2];
        float cc = chpn_sigmoid(gf) * c_st[b2 * kNH + j] + chpn_sigmoid(gi) * chpn_tanh(gc);
        float hh = chpn_sigmoid(go) * chpn_tanh(cc);
        c_st[b2 * kNH + j] = cc;
        h_dst[b2 * kNH + j] = hh;
    }
}

// ------- query = h_d @ wq^T ; zero ctx accumulators ----------------------
__global__ void chpn_query(
    const float* wqT, const float* h_src,
    float* query, float* ctx_num, float* denom)
{
    __shared__ float hl[kNH];
    int bb = blockIdx.x, tid = threadIdx.x;
    hl[tid] = h_src[bb * kNH + tid];
    __syncthreads();
    float acc = 0.f;
    for (int j = 0; j < kNH; ++j)
        acc = fmaf(hl[j], wqT[(size_t)j * kNH + tid], acc);
    query[bb * kNH + tid] = acc;
    ctx_num[bb * kNH + tid] = 0.0f;
    if (tid == 0) denom[bb] = 0.0f;
}

// ---------------- scores (f32 OUT) + exp + context partials --------------
__global__ void chpn_score_ctx(
    const float* keysT, const float* enc_outs,
    const float* query, const float* vvec,
    float* ctx_num, float* denom,
    float* out, int t)
{
    __shared__ float ql[kNH], vl[kNH];
    __shared__ float part[4][64];
    __shared__ float el[64];
    int bid = blockIdx.x;
    int bb = bid >> 3, sc = bid & 7;
    int s0 = sc * 64;
    int tid = threadIdx.x;
    int s = tid & 63, hq = tid >> 6;

    ql[tid] = query[bb * kNH + tid];     ql[tid + 256] = query[bb * kNH + tid + 256];
    vl[tid] = vvec[tid];                 vl[tid + 256] = vvec[tid + 256];
    __syncthreads();

    float acc = 0.f;
    const float* kp = keysT + (size_t)bb * kNH * kNS + s0 + s;
    const int h0 = hq * 128;
    for (int h = h0; h < h0 + 128; ++h) {
        float kv = kp[(size_t)h * kNS];
        acc = fmaf(vl[h], chpn_tanh(ql[h] + kv), acc);
    }
    part[hq][s] = acc;
    __syncthreads();

    if (hq == 0) {
        float scv = part[0][s] + part[1][s] + part[2][s] + part[3][s];
        out[((size_t)bb * kNT + t) * kNS + s0 + s] = scv;     // f32 output
        float e = __expf(scv);          // scores are tiny; no max-sub needed
        el[s] = e;
        float wsum = e;
        for (int off = 32; off > 0; off >>= 1) wsum += __shfl_down(wsum, off);
        if (s == 0) atomicAdd(&denom[bb], wsum);
    }
    __syncthreads();

    float a0 = 0.f, a1 = 0.f;
    const float* ep = enc_outs + ((size_t)bb * kNS + s0) * kNH;
    for (int ss = 0; ss < 64; ++ss) {
        float ev = el[ss];
        a0 = fmaf(ev, ep[(size_t)ss * kNH + tid], a0);
        a1 = fmaf(ev, ep[(size_t)ss * kNH + tid + 256], a1);
    }
    atomicAdd(&ctx_num[bb * kNH + tid], a0);
    atomicAdd(&ctx_num[bb * kNH + tid + 256], a1);
}

extern "C" void kernel_launch(void* const* d_in, const int* in_sizes, int n_in,
                              void* d_out, int out_size, void* d_ws, size_t ws_size,
                              hipStream_t stream) {
    const float* inputs = (const float*)d_in[0];
    const float* e_wih  = (const float*)d_in[1];
    const float* e_whh  = (const float*)d_in[2];
    const float* e_bih  = (const float*)d_in[3];
    const float* e_bhh  = (const float*)d_in[4];
    const float* d_wih  = (const float*)d_in[5];
    const float* d_whh  = (const float*)d_in[6];
    const float* d_bih  = (const float*)d_in[7];
    const float* d_bhh  = (const float*)d_in[8];
    const float* w_key  = (const float*)d_in[9];
    const float* w_qry  = (const float*)d_in[10];
    const float* v_vec  = (const float*)d_in[11];
    float* out = (float*)d_out;        // OUTPUT IS FLOAT32 (64 MB allocation)

    // f32 staging: state ~1.8MB + keysF 67MB + encF 67MB of 256MB ws
    float* wsf   = (float*)d_ws;
    float* h0    = wsf;
    float* cst   = h0 + kNB * kNH;
    float* h1    = cst + kNB * kNH;
    float* query = h1 + kNB * kNH;
    float* ctxn  = query + kNB * kNH;
    float* denom = ctxn + kNB * kNH;
    float* encb  = denom + 64;
    float* decb  = encb + kNG;
    float* wqT   = decb + kNG;
    float* keysF = wqT + (size_t)kNH * kNH;
    float* encF  = keysF + (size_t)kNB * kNH * kNS;

    ConvexHullPointerNetwork_57303453663418_kernel<<<1024, 256, 0, stream>>>(
        e_bih, e_bhh, d_bih, d_bhh, w_qry, encb, decb, wqT, h0);

    for (int t = 0; t < kNS; ++t) {
        float* hs = (t & 1) ? h1 : h0;
        float* hd = (t & 1) ? h0 : h1;
        chpn_enc_cell<<<256, 256, 0, stream>>>(inputs, e_wih, e_whh, encb,
                                               hs, hd, cst, encF, t);
    }

    chpn_keys_gemm<<<4096, 256, 0, stream>>>(encF, w_key, keysF);

    for (int t = 0; t < kNT; ++t) {
        float* hs = (t & 1) ? h1 : h0;
        float* hd = (t & 1) ? h0 : h1;
        chpn_dec_cell<<<256, 256, 0, stream>>>(d_wih, d_whh, decb,
                                               hs, hd, cst,
                                               ctxn, denom, t == 0 ? 1 : 0);
        chpn_query<<<64, 512, 0, stream>>>(wqT, hd, query, ctxn, denom);
        chpn_score_ctx<<<512, 256, 0, stream>>>(keysF, encF, query, v_vec,
                                                ctxn, denom, out, t);
    }

    // one-time confirmation print (live only; no-op under graph capture)
    hipStreamCaptureStatus cap = hipStreamCaptureStatusNone;
    if (hipStreamIsCapturing(stream, &cap) == hipSuccess &&
        cap == hipStreamCaptureStatusNone && !g_once) {
        g_once = 1;
        (void)hipStreamSynchronize(stream);
        float h4[4] = {0, 0, 0, 0};
        (void)hipMemcpy(h4, out, 16, hipMemcpyDeviceToHost);
        fprintf(stderr, "[CHPN] f32 out head: %.6f %.6f %.6f %.6f\n",
                h4[0], h4[1], h4[2], h4[3]);
        fflush(stderr);
    }
}

// Round 28
// 70882.080 us; speedup vs baseline: 1.2549x; 1.2549x over previous
//
#include <hip/hip_runtime.h>

constexpr int kNB = 64;    // batch
constexpr int kNS = 512;   // encoder sequence length
constexpr int kNH = 512;   // hidden dim
constexpr int kNG = 2048;  // 4*kNH gate rows
constexpr int kNT = 512;   // decoder steps

__device__ __forceinline__ float chpn_sigmoid(float x) {
    return 1.0f / (1.0f + __expf(-x));
}
__device__ __forceinline__ float chpn_tanh(float x) {
    x = fmaxf(fminf(x, 15.0f), -15.0f);
    float e = __expf(2.0f * x);
    return (e - 1.0f) / (e + 1.0f);
}

// ------- init: zero h0/c, fused biases, transposed W_query ---------------
__global__ void ConvexHullPointerNetwork_57303453663418_kernel(
    const float* ebih, const float* ebhh,
    const float* dbih, const float* dbhh,
    const float* wq,
    float* enc_b, float* dec_b, float* wqT, float* h0c)
{
    int i = blockIdx.x * 256 + threadIdx.x;
    if (i < kNG) { enc_b[i] = ebih[i] + ebhh[i]; dec_b[i] = dbih[i] + dbhh[i]; }
    if (i < 2 * kNB * kNH) h0c[i] = 0.0f;
    if (i < kNH * kNH) {
        int r = i >> 9, c = i & 511;
        wqT[c * kNH + r] = wq[i];
    }
}

// ---------------- encoder cell: 512 blocks (1 j-dim), 256 thr = (b,gate) --
__global__ __launch_bounds__(256) void chpn_enc_cell(
    const float* __restrict__ inputs, const float* __restrict__ wih,
    const float* __restrict__ whh, const float* __restrict__ bias,
    const float* __restrict__ h_src, float* __restrict__ h_dst,
    float* __restrict__ c_st, float* __restrict__ enc_outs, int t)
{
    __shared__ float tile[64][65];          // [k][batch]
    __shared__ float gate_lds[4][64];
    const int tid = threadIdx.x;
    const int bb = tid & 63, gg = tid >> 6;
    const int j = (int)blockIdx.x;

    const int r = gg * kNH + j;
    const float* w = whh + (size_t)r * kNH;
    float acc = 0.f;

    for (int ch = 0; ch < 8; ++ch) {
        const int k0 = ch * 64;
        for (int i = 0; i < 16; ++i) {
            int e = tid + i * 256; int kk = e & 63, b2 = e >> 6;
            tile[kk][b2] = h_src[b2 * kNH + k0 + kk];
        }
        __syncthreads();
        #pragma unroll
        for (int kk = 0; kk < 64; ++kk)
            acc = fmaf(tile[kk][bb], w[k0 + kk], acc);
        __syncthreads();
    }
    float x0 = inputs[(bb * kNS + t) * 2 + 0];
    float x1 = inputs[(bb * kNS + t) * 2 + 1];
    acc += bias[r] + wih[r * 2] * x0 + wih[r * 2 + 1] * x1;

    gate_lds[gg][bb] = acc;
    __syncthreads();
    if (tid < 64) {
        float gi = gate_lds[0][tid], gf = gate_lds[1][tid];
        float gc = gate_lds[2][tid], go = gate_lds[3][tid];
        float cc = chpn_sigmoid(gf) * c_st[tid * kNH + j] + chpn_sigmoid(gi) * chpn_tanh(gc);
        float hh = chpn_sigmoid(go) * chpn_tanh(cc);
        c_st[tid * kNH + j] = cc;
        h_dst[tid * kNH + j] = hh;
        enc_outs[((size_t)tid * kNS + t) * kNH + j] = hh;
    }
}

// -------- keysT[b][h][s] GEMM (f32) --------------------------------------
__global__ __launch_bounds__(256) void chpn_keys_gemm(
    const float* __restrict__ enc_outs, const float* __restrict__ wk,
    float* __restrict__ keysT)
{
    int bid = blockIdx.x;
    int bb = bid >> 6, ht = (bid >> 3) & 7, st = bid & 7;
    __shared__ float asb[32][66];
    __shared__ float bsb[32][66];
    int tid = threadIdx.x;
    int tx = tid & 15, ty = tid >> 4;
    float acc[4][4] = {};
    for (int j0 = 0; j0 < kNH; j0 += 32) {
        for (int i = 0; i < 8; ++i) {
            int e = tid + i * 256;
            int j = e & 31, s = e >> 5;
            asb[j][s] = enc_outs[((size_t)bb * kNS + st * 64 + s) * kNH + j0 + j];
            bsb[j][s] = wk[(size_t)(ht * 64 + s) * kNH + j0 + j];
        }
        __syncthreads();
        #pragma unroll 8
        for (int j = 0; j < 32; ++j) {
            float a0 = asb[j][tx*4], a1 = asb[j][tx*4+1], a2 = asb[j][tx*4+2], a3 = asb[j][tx*4+3];
            float b0 = bsb[j][ty*4], b1 = bsb[j][ty*4+1], b2 = bsb[j][ty*4+2], b3 = bsb[j][ty*4+3];
            acc[0][0] = fmaf(b0,a0,acc[0][0]); acc[0][1] = fmaf(b0,a1,acc[0][1]);
            acc[0][2] = fmaf(b0,a2,acc[0][2]); acc[0][3] = fmaf(b0,a3,acc[0][3]);
            acc[1][0] = fmaf(b1,a0,acc[1][0]); acc[1][1] = fmaf(b1,a1,acc[1][1]);
            acc[1][2] = fmaf(b1,a2,acc[1][2]); acc[1][3] = fmaf(b1,a3,acc[1][3]);
            acc[2][0] = fmaf(b2,a0,acc[2][0]); acc[2][1] = fmaf(b2,a1,acc[2][1]);
            acc[2][2] = fmaf(b2,a2,acc[2][2]); acc[2][3] = fmaf(b2,a3,acc[2][3]);
            acc[3][0] = fmaf(b3,a0,acc[3][0]); acc[3][1] = fmaf(b3,a1,acc[3][1]);
            acc[3][2] = fmaf(b3,a2,acc[3][2]); acc[3][3] = fmaf(b3,a3,acc[3][3]);
        }
        __syncthreads();
    }
    for (int i = 0; i < 4; ++i)
        for (int k = 0; k < 4; ++k)
            keysT[((size_t)bb * kNH + ht * 64 + ty * 4 + i) * kNS + st * 64 + tx * 4 + k] =
                acc[i][k];
}

// ------- decoder cell: 512 blocks (1 j-dim), 256 thr = (b,gate) ----------
__global__ __launch_bounds__(256) void chpn_dec_cell(
    const float* __restrict__ wih, const float* __restrict__ whh,
    const float* __restrict__ bias,
    const float* __restrict__ h_src, float* __restrict__ h_dst,
    float* __restrict__ c_st,
    const float* __restrict__ ctx_num, const float* __restrict__ denom,
    int first)
{
    __shared__ float tile[64][65];
    __shared__ float gate_lds[4][64];
    __shared__ float invd[64];
    const int tid = threadIdx.x;
    const int bb = tid & 63, gg = tid >> 6;
    const int j = (int)blockIdx.x;
    if (tid < 64) invd[tid] = first ? 0.0f : (1.0f / denom[tid]);
    __syncthreads();

    const int r = gg * kNH + j;
    float acc = 0.f;
    {   // x half (context)
        const float* w = wih + (size_t)r * kNH;
        for (int ch = 0; ch < 8; ++ch) {
            const int k0 = ch * 64;
            for (int i = 0; i < 16; ++i) {
                int e = tid + i * 256; int kk = e & 63, b2 = e >> 6;
                tile[kk][b2] = first ? 0.0f : ctx_num[b2 * kNH + k0 + kk] * invd[b2];
            }
            __syncthreads();
            #pragma unroll
            for (int kk = 0; kk < 64; ++kk)
                acc = fmaf(tile[kk][bb], w[k0 + kk], acc);
            __syncthreads();
        }
    }
    {   // h half
        const float* w = whh + (size_t)r * kNH;
        for (int ch = 0; ch < 8; ++ch) {
            const int k0 = ch * 64;
            for (int i = 0; i < 16; ++i) {
                int e = tid + i * 256; int kk = e & 63, b2 = e >> 6;
                tile[kk][b2] = h_src[b2 * kNH + k0 + kk];
            }
            __syncthreads();
            #pragma unroll
            for (int kk = 0; kk < 64; ++kk)
                acc = fmaf(tile[kk][bb], w[k0 + kk], acc);
            __syncthreads();
        }
    }
    acc += bias[r];
    gate_lds[gg][bb] = acc;
    __syncthreads();
    if (tid < 64) {
        float gi = gate_lds[0][tid], gf = gate_lds[1][tid];
        float gc = gate_lds[2][tid], go = gate_lds[3][tid];
        float cc = chpn_sigmoid(gf) * c_st[tid * kNH + j] + chpn_sigmoid(gi) * chpn_tanh(gc);
        float hh = chpn_sigmoid(go) * chpn_tanh(cc);
        c_st[tid * kNH + j] = cc;
        h_dst[tid * kNH + j] = hh;
    }
}

// ------- query: 256 blocks = (b, hc of 128 h), 256 thr (h x j-half) ------
__global__ __launch_bounds__(256) void chpn_query(
    const float* __restrict__ wqT, const float* __restrict__ h_src,
    float* __restrict__ query, float* __restrict__ ctx_num,
    float* __restrict__ denom)
{
    __shared__ float hl[kNH];
    __shared__ float part[256];
    int bid = blockIdx.x;
    int bb = bid >> 2, hc = bid & 3;
    int tid = threadIdx.x;
    int hl_idx = tid;
    hl[hl_idx] = h_src[bb * kNH + hl_idx];
    hl[hl_idx + 256] = h_src[bb * kNH + hl_idx + 256];
    __syncthreads();

    int h = hc * 128 + (tid & 127);
    int jh = tid >> 7;                       // j-half: 0 or 1
    float acc = 0.f;
    const float* wcol = wqT + h;
    #pragma unroll 8
    for (int j = jh * 256; j < jh * 256 + 256; ++j)
        acc = fmaf(hl[j], wcol[(size_t)j * kNH], acc);
    part[tid] = acc;
    __syncthreads();
    if (tid < 128) {
        float q = part[tid] + part[tid + 128];
        query[bb * kNH + h] = q;
        ctx_num[bb * kNH + h] = 0.0f;
        if (hc == 0 && tid == 0) denom[bb] = 0.0f;
    }
}

// ------- scores + exp + context: 512 blocks x 1024 thr -------------------
__global__ __launch_bounds__(1024) void chpn_score_ctx(
    const float* __restrict__ keysT, const float* __restrict__ enc_outs,
    const float* __restrict__ query, const float* __restrict__ vvec,
    float* __restrict__ ctx_num, float* __restrict__ denom,
    float* __restrict__ out, int t)
{
    __shared__ float ql[kNH], vl[kNH];
    __shared__ float part[16][64];
    __shared__ float el[64];
    int bid = blockIdx.x;
    int bb = bid >> 3, sc = bid & 7;
    int s0 = sc * 64;
    int tid = threadIdx.x;
    int s = tid & 63, hq = tid >> 6;         // hq in 0..15, 32 h each

    if (tid < kNH) { ql[tid] = query[bb * kNH + tid]; vl[tid] = vvec[tid]; }
    __syncthreads();

    float acc = 0.f;
    const float* kp = keysT + (size_t)bb * kNH * kNS + s0 + s;
    const int h0 = hq * 32;
    #pragma unroll 4
    for (int h = h0; h < h0 + 32; ++h) {
        float kv = kp[(size_t)h * kNS];
        acc = fmaf(vl[h], chpn_tanh(ql[h] + kv), acc);
    }
    part[hq][s] = acc;
    __syncthreads();

    if (tid < 64) {                           // single wave: s = tid
        float scv = 0.f;
        #pragma unroll
        for (int q = 0; q < 16; ++q) scv += part[q][tid];
        out[((size_t)bb * kNT + t) * kNS + s0 + tid] = scv;   // f32 output
        float e = __expf(scv);                // scores tiny; no max-sub
        el[tid] = e;
        float wsum = e;
        #pragma unroll
        for (int off = 32; off > 0; off >>= 1) wsum += __shfl_down(wsum, off);
        if (tid == 0) atomicAdd(&denom[bb], wsum);
    }
    __syncthreads();

    // context partials: 1024 thr = (j 0..511) x (ss-half 0..1)
    int j = tid & 511, sh = tid >> 9;
    float a = 0.f;
    const float* ep = enc_outs + ((size_t)bb * kNS + s0 + sh * 32) * kNH + j;
    #pragma unroll 4
    for (int ss = 0; ss < 32; ++ss)
        a = fmaf(el[sh * 32 + ss], ep[(size_t)ss * kNH], a);
    atomicAdd(&ctx_num[bb * kNH + j], a);
}

extern "C" void kernel_launch(void* const* d_in, const int* in_sizes, int n_in,
                              void* d_out, int out_size, void* d_ws, size_t ws_size,
                              hipStream_t stream) {
    const float* inputs = (const float*)d_in[0];
    const float* e_wih  = (const float*)d_in[1];
    const float* e_whh  = (const float*)d_in[2];
    const float* e_bih  = (const float*)d_in[3];
    const float* e_bhh  = (const float*)d_in[4];
    const float* d_wih  = (const float*)d_in[5];
    const float* d_whh  = (const float*)d_in[6];
    const float* d_bih  = (const float*)d_in[7];
    const float* d_bhh  = (const float*)d_in[8];
    const float* w_key  = (const float*)d_in[9];
    const float* w_qry  = (const float*)d_in[10];
    const float* v_vec  = (const float*)d_in[11];
    float* out = (float*)d_out;               // f32 output (64 MB)

    float* wsf   = (float*)d_ws;
    float* h0    = wsf;
    float* cst   = h0 + kNB * kNH;
    float* h1    = cst + kNB * kNH;
    float* query = h1 + kNB * kNH;
    float* ctxn  = query + kNB * kNH;
    float* denom = ctxn + kNB * kNH;
    float* encb  = denom + 64;
    float* decb  = encb + kNG;
    float* wqT   = decb + kNG;
    float* keysF = wqT + (size_t)kNH * kNH;
    float* encF  = keysF + (size_t)kNB * kNH * kNS;

    ConvexHullPointerNetwork_57303453663418_kernel<<<1024, 256, 0, stream>>>(
        e_bih, e_bhh, d_bih, d_bhh, w_qry, encb, decb, wqT, h0);

    for (int t = 0; t < kNS; ++t) {
        float* hs = (t & 1) ? h1 : h0;
        float* hd = (t & 1) ? h0 : h1;
        chpn_enc_cell<<<512, 256, 0, stream>>>(inputs, e_wih, e_whh, encb,
                                               hs, hd, cst, encF, t);
    }

    chpn_keys_gemm<<<4096, 256, 0, stream>>>(encF, w_key, keysF);

    for (int t = 0; t < kNT; ++t) {
        float* hs = (t & 1) ? h1 : h0;
        float* hd = (t & 1) ? h0 : h1;
        chpn_dec_cell<<<512, 256, 0, stream>>>(d_wih, d_whh, decb,
                                               hs, hd, cst,
                                               ctxn, denom, t == 0 ? 1 : 0);
        chpn_query<<<256, 256, 0, stream>>>(wqT, hd, query, ctxn, denom);
        chpn_score_ctx<<<512, 1024, 0, stream>>>(keysF, encF, query, v_vec,
                                                 ctxn, denom, out, t);
    }
}